// Round 1
// baseline (787.071 us; speedup 1.0000x reference)
//
#include <hip/hip_runtime.h>
#include <hip/hip_bf16.h>
#include <cstdint>

#define D_IN 128
#define DK 32
#define NH 8
#define HD 256  // NH*DK

// ---------------- QKV projection: 8 nodes per block ----------------
__global__ __launch_bounds__(256) void qkv_kernel(
    const float* __restrict__ h, const float* __restrict__ WQ,
    const float* __restrict__ WK, const float* __restrict__ WV,
    float* __restrict__ Q, float* __restrict__ K, float* __restrict__ V,
    int n_node) {
  __shared__ float hs[D_IN * 8];  // hs[d*8 + i]
  int tid = threadIdx.x;
  int base = blockIdx.x * 8;
  for (int t = tid; t < 8 * D_IN; t += 256) {
    int node = t >> 7;
    int d = t & 127;
    float v = 0.f;
    if (base + node < n_node) v = h[(size_t)(base + node) * D_IN + d];
    hs[d * 8 + node] = v;
  }
  __syncthreads();
  int head = tid >> 5;
  int kk = tid & 31;
  const float* wq = WQ + head * (D_IN * DK) + kk;
  const float* wk = WK + head * (D_IN * DK) + kk;
  const float* wv = WV + head * (D_IN * DK) + kk;
  float qa[8] = {0,0,0,0,0,0,0,0};
  float ka[8] = {0,0,0,0,0,0,0,0};
  float va[8] = {0,0,0,0,0,0,0,0};
  #pragma unroll 4
  for (int d = 0; d < D_IN; d++) {
    float w0 = wq[d * 32];
    float w1 = wk[d * 32];
    float w2 = wv[d * 32];
    const float4* hp = (const float4*)(hs + d * 8);
    float4 h0 = hp[0], h1 = hp[1];
    float hv[8] = {h0.x, h0.y, h0.z, h0.w, h1.x, h1.y, h1.z, h1.w};
    #pragma unroll
    for (int i = 0; i < 8; i++) {
      qa[i] += hv[i] * w0;
      ka[i] += hv[i] * w1;
      va[i] += hv[i] * w2;
    }
  }
  #pragma unroll
  for (int i = 0; i < 8; i++) {
    if (base + i < n_node) {
      size_t o = (size_t)(base + i) * HD + tid;
      Q[o] = qa[i]; K[o] = ka[i]; V[o] = va[i];
    }
  }
}

// ---------------- CSR build ----------------
__global__ void hist_kernel(const int* __restrict__ row, int n_edge,
                            int* __restrict__ cnt) {
  int i = blockIdx.x * blockDim.x + threadIdx.x;
  if (i < n_edge) atomicAdd(&cnt[row[i]], 1);
}

__global__ __launch_bounds__(256) void scan1_kernel(
    const int* __restrict__ cnt, int n, int* __restrict__ exc,
    int* __restrict__ bsum) {
  __shared__ int s[256];
  int gid = blockIdx.x * 256 + threadIdx.x;
  int v = (gid < n) ? cnt[gid] : 0;
  s[threadIdx.x] = v;
  __syncthreads();
  #pragma unroll
  for (int off = 1; off < 256; off <<= 1) {
    int t = (threadIdx.x >= off) ? s[threadIdx.x - off] : 0;
    __syncthreads();
    s[threadIdx.x] += t;
    __syncthreads();
  }
  if (gid < n) exc[gid] = s[threadIdx.x] - v;  // exclusive within block
  if (threadIdx.x == 255) bsum[blockIdx.x] = s[255];
}

__global__ __launch_bounds__(256) void scan2_kernel(int* __restrict__ bsum,
                                                    int nb) {
  __shared__ int s[256];
  int v = (threadIdx.x < nb) ? bsum[threadIdx.x] : 0;
  s[threadIdx.x] = v;
  __syncthreads();
  #pragma unroll
  for (int off = 1; off < 256; off <<= 1) {
    int t = (threadIdx.x >= off) ? s[threadIdx.x - off] : 0;
    __syncthreads();
    s[threadIdx.x] += t;
    __syncthreads();
  }
  if (threadIdx.x < nb) bsum[threadIdx.x] = s[threadIdx.x] - v;  // exclusive
}

__global__ __launch_bounds__(256) void scan3_kernel(
    int* __restrict__ exc, const int* __restrict__ bsum, int n, int n_edge,
    int* __restrict__ cursor) {
  int gid = blockIdx.x * 256 + threadIdx.x;
  if (gid < n) {
    int o = exc[gid] + bsum[blockIdx.x];
    exc[gid] = o;
    cursor[gid] = o;
  }
  if (gid == 0) exc[n] = n_edge;
}

__global__ void scatter_kernel(const int* __restrict__ row,
                               const int* __restrict__ col, int n_edge,
                               int* __restrict__ cursor,
                               int* __restrict__ col_sorted) {
  int i = blockIdx.x * blockDim.x + threadIdx.x;
  if (i < n_edge) {
    int pos = atomicAdd(&cursor[row[i]], 1);
    col_sorted[pos] = col[i];
  }
}

// ---------------- Main attention: one block per destination node ----------------
#define CHUNK 64
__global__ __launch_bounds__(256) void attn_kernel(
    const float* __restrict__ Q, const float* __restrict__ K,
    const float* __restrict__ V, const int* __restrict__ offsets,
    const int* __restrict__ col_sorted, float* __restrict__ out, int n_node) {
  int node = blockIdx.x;
  int tid = threadIdx.x;
  int head = tid >> 5;
  int lane = tid & 31;
  __shared__ float qs[HD];
  __shared__ int cols[CHUNK];
  __shared__ float ex[NH][CHUNK];
  qs[tid] = Q[(size_t)node * HD + tid];
  int start = offsets[node], end = offsets[node + 1];
  __syncthreads();
  float4 qv[8];
  #pragma unroll
  for (int i = 0; i < 8; i++) qv[i] = ((const float4*)(qs + head * 32))[i];

  float m = -INFINITY, denom = 0.f, acc = 0.f;
  for (int base = start; base < end; base += CHUNK) {
    int n = min(CHUNK, end - base);
    __syncthreads();  // protect cols/ex reuse across chunks
    if (tid < n) cols[tid] = col_sorted[base + tid];
    __syncthreads();
    float lmax = -INFINITY;
    for (int j = lane; j < n; j += 32) {
      const float4* kp = (const float4*)(K + (size_t)cols[j] * HD + head * 32);
      float e = 0.f;
      #pragma unroll
      for (int i = 0; i < 8; i++) {
        float4 kv = kp[i];
        e += qv[i].x * kv.x + qv[i].y * kv.y + qv[i].z * kv.z + qv[i].w * kv.w;
      }
      e *= 0.17677669529663687f;  // 1/sqrt(32)
      ex[head][j] = e;
      lmax = fmaxf(lmax, e);
    }
    #pragma unroll
    for (int off = 16; off; off >>= 1)
      lmax = fmaxf(lmax, __shfl_xor(lmax, off, 32));
    float nm = fmaxf(m, lmax);
    float scale = __expf(m - nm);  // first chunk: exp(-inf)=0
    denom *= scale;
    acc *= scale;
    float lsum = 0.f;
    for (int j = lane; j < n; j += 32) {
      float e = __expf(ex[head][j] - nm);
      ex[head][j] = e;
      lsum += e;
    }
    #pragma unroll
    for (int off = 16; off; off >>= 1)
      lsum += __shfl_xor(lsum, off, 32);
    denom += lsum;
    m = nm;
    __syncthreads();  // ex visible to whole block (cheap, uniform)
    for (int j = 0; j < n; j++) {
      float w = ex[head][j];
      acc += w * V[(size_t)cols[j] * HD + head * 32 + lane];
    }
  }
  float res = (end > start) ? acc / denom : 0.f;
  out[(size_t)node * HD + tid] = res;
}

extern "C" void kernel_launch(void* const* d_in, const int* in_sizes, int n_in,
                              void* d_out, int out_size, void* d_ws,
                              size_t ws_size, hipStream_t stream) {
  const float* h = (const float*)d_in[0];
  const int* edge = (const int*)d_in[1];
  const float* WQ = (const float*)d_in[2];
  const float* WK = (const float*)d_in[3];
  const float* WV = (const float*)d_in[4];
  float* out = (float*)d_out;

  int n_node = in_sizes[0] / D_IN;
  int n_edge = in_sizes[1] / 2;
  const int* row = edge;
  const int* col = edge + n_edge;

  char* ws = (char*)d_ws;
  size_t off = 0;
  auto alloc = [&](size_t bytes) {
    void* p = ws + off;
    off += (bytes + 255) & ~(size_t)255;
    return p;
  };
  float* Q = (float*)alloc((size_t)n_node * HD * 4);
  float* K = (float*)alloc((size_t)n_node * HD * 4);
  float* V = (float*)alloc((size_t)n_node * HD * 4);
  int* col_sorted = (int*)alloc((size_t)n_edge * 4);
  int* cnt = (int*)alloc((size_t)n_node * 4);
  int* offsets = (int*)alloc((size_t)(n_node + 1) * 4);
  int* cursor = (int*)alloc((size_t)n_node * 4);
  int* bsum = (int*)alloc(256 * 4);

  hipMemsetAsync(cnt, 0, (size_t)n_node * 4, stream);

  int nb_nodes8 = (n_node + 7) / 8;
  qkv_kernel<<<nb_nodes8, 256, 0, stream>>>(h, WQ, WK, WV, Q, K, V, n_node);

  int nb_e = (n_edge + 255) / 256;
  hist_kernel<<<nb_e, 256, 0, stream>>>(row, n_edge, cnt);

  int nb = (n_node + 255) / 256;  // 196 <= 256
  scan1_kernel<<<nb, 256, 0, stream>>>(cnt, n_node, offsets, bsum);
  scan2_kernel<<<1, 256, 0, stream>>>(bsum, nb);
  scan3_kernel<<<nb, 256, 0, stream>>>(offsets, bsum, n_node, n_edge, cursor);

  scatter_kernel<<<nb_e, 256, 0, stream>>>(row, col, n_edge, cursor, col_sorted);

  attn_kernel<<<n_node, 256, 0, stream>>>(Q, K, V, offsets, col_sorted, out,
                                          n_node);
}

// Round 2
// 625.672 us; speedup vs baseline: 1.2580x; 1.2580x over previous
//
#include <hip/hip_runtime.h>
#include <hip/hip_bf16.h>
#include <cstdint>

#define D_IN 128
#define DK 32
#define NH 8
#define HD 256  // NH*DK

typedef __attribute__((ext_vector_type(8))) short short8;

__device__ inline float bf2f(unsigned short u) {
  union { unsigned int i; float f; } c;
  c.i = ((unsigned int)u) << 16;
  return c.f;
}

// ---------------- QKV projection: 8 nodes per block, bf16 output ----------------
__global__ __launch_bounds__(256) void qkv_kernel(
    const float* __restrict__ h, const float* __restrict__ WQ,
    const float* __restrict__ WK, const float* __restrict__ WV,
    __hip_bfloat16* __restrict__ Q, __hip_bfloat16* __restrict__ K,
    __hip_bfloat16* __restrict__ V, int n_node) {
  __shared__ float hs[D_IN * 8];  // hs[d*8 + i]
  int tid = threadIdx.x;
  int base = blockIdx.x * 8;
  for (int t = tid; t < 8 * D_IN; t += 256) {
    int node = t >> 7;
    int d = t & 127;
    float v = 0.f;
    if (base + node < n_node) v = h[(size_t)(base + node) * D_IN + d];
    hs[d * 8 + node] = v;
  }
  __syncthreads();
  int head = tid >> 5;
  int kk = tid & 31;
  const float* wq = WQ + head * (D_IN * DK) + kk;
  const float* wk = WK + head * (D_IN * DK) + kk;
  const float* wv = WV + head * (D_IN * DK) + kk;
  float qa[8] = {0,0,0,0,0,0,0,0};
  float ka[8] = {0,0,0,0,0,0,0,0};
  float va[8] = {0,0,0,0,0,0,0,0};
  #pragma unroll 4
  for (int d = 0; d < D_IN; d++) {
    float w0 = wq[d * 32];
    float w1 = wk[d * 32];
    float w2 = wv[d * 32];
    const float4* hp = (const float4*)(hs + d * 8);
    float4 h0 = hp[0], h1 = hp[1];
    float hv[8] = {h0.x, h0.y, h0.z, h0.w, h1.x, h1.y, h1.z, h1.w};
    #pragma unroll
    for (int i = 0; i < 8; i++) {
      qa[i] += hv[i] * w0;
      ka[i] += hv[i] * w1;
      va[i] += hv[i] * w2;
    }
  }
  #pragma unroll
  for (int i = 0; i < 8; i++) {
    if (base + i < n_node) {
      size_t o = (size_t)(base + i) * HD + tid;
      Q[o] = __float2bfloat16(qa[i]);
      K[o] = __float2bfloat16(ka[i]);
      V[o] = __float2bfloat16(va[i]);
    }
  }
}

// ---------------- CSR build ----------------
__global__ void hist_kernel(const int* __restrict__ row, int n_edge,
                            int* __restrict__ cnt) {
  int i = blockIdx.x * blockDim.x + threadIdx.x;
  if (i < n_edge) atomicAdd(&cnt[row[i]], 1);
}

__global__ __launch_bounds__(256) void scan1_kernel(
    const int* __restrict__ cnt, int n, int* __restrict__ exc,
    int* __restrict__ bsum) {
  __shared__ int s[256];
  int gid = blockIdx.x * 256 + threadIdx.x;
  int v = (gid < n) ? cnt[gid] : 0;
  s[threadIdx.x] = v;
  __syncthreads();
  #pragma unroll
  for (int off = 1; off < 256; off <<= 1) {
    int t = (threadIdx.x >= off) ? s[threadIdx.x - off] : 0;
    __syncthreads();
    s[threadIdx.x] += t;
    __syncthreads();
  }
  if (gid < n) exc[gid] = s[threadIdx.x] - v;  // exclusive within block
  if (threadIdx.x == 255) bsum[blockIdx.x] = s[255];
}

__global__ __launch_bounds__(256) void scan2_kernel(int* __restrict__ bsum,
                                                    int nb) {
  __shared__ int s[256];
  int v = (threadIdx.x < nb) ? bsum[threadIdx.x] : 0;
  s[threadIdx.x] = v;
  __syncthreads();
  #pragma unroll
  for (int off = 1; off < 256; off <<= 1) {
    int t = (threadIdx.x >= off) ? s[threadIdx.x - off] : 0;
    __syncthreads();
    s[threadIdx.x] += t;
    __syncthreads();
  }
  if (threadIdx.x < nb) bsum[threadIdx.x] = s[threadIdx.x] - v;  // exclusive
}

__global__ __launch_bounds__(256) void scan3_kernel(
    int* __restrict__ exc, const int* __restrict__ bsum, int n, int n_edge,
    int* __restrict__ cursor) {
  int gid = blockIdx.x * 256 + threadIdx.x;
  if (gid < n) {
    int o = exc[gid] + bsum[blockIdx.x];
    exc[gid] = o;
    cursor[gid] = o;
  }
  if (gid == 0) exc[n] = n_edge;
}

__global__ void scatter_kernel(const int* __restrict__ row,
                               const int* __restrict__ col, int n_edge,
                               int* __restrict__ cursor,
                               int* __restrict__ col_sorted) {
  int i = blockIdx.x * blockDim.x + threadIdx.x;
  if (i < n_edge) {
    int pos = atomicAdd(&cursor[row[i]], 1);
    col_sorted[pos] = col[i];
  }
}

// ---------------- Main attention: one block per destination node ----------------
#define CHUNK 64
__global__ __launch_bounds__(256) void attn_kernel(
    const __hip_bfloat16* __restrict__ Q, const __hip_bfloat16* __restrict__ K,
    const __hip_bfloat16* __restrict__ V, const int* __restrict__ offsets,
    const int* __restrict__ col_sorted, float* __restrict__ out, int n_node) {
  int node = blockIdx.x;
  int tid = threadIdx.x;
  int head = tid >> 5;
  int lane = tid & 31;
  __shared__ int cols[CHUNK];
  __shared__ float ex[NH][CHUNK];
  int start = offsets[node], end = offsets[node + 1];

  // Q fragment for this head (broadcast read: 32 lanes read same 64B)
  float qf[32];
  {
    const short8* qp = (const short8*)(Q + (size_t)node * HD + head * 32);
    #pragma unroll
    for (int i = 0; i < 4; i++) {
      short8 qv = qp[i];
      #pragma unroll
      for (int r = 0; r < 8; r++) qf[i * 8 + r] = bf2f((unsigned short)qv[r]);
    }
  }

  float m = -INFINITY, denom = 0.f, acc = 0.f;
  for (int base = start; base < end; base += CHUNK) {
    int n = min(CHUNK, end - base);
    __syncthreads();  // protect cols/ex reuse across chunks
    if (tid < n) cols[tid] = col_sorted[base + tid];
    __syncthreads();
    float lmax = -INFINITY;
    for (int j = lane; j < n; j += 32) {
      const short8* kp = (const short8*)(K + (size_t)cols[j] * HD + head * 32);
      float e = 0.f;
      #pragma unroll
      for (int i = 0; i < 4; i++) {
        short8 kv = kp[i];
        #pragma unroll
        for (int r = 0; r < 8; r++)
          e += qf[i * 8 + r] * bf2f((unsigned short)kv[r]);
      }
      e *= 0.17677669529663687f;  // 1/sqrt(32)
      ex[head][j] = e;
      lmax = fmaxf(lmax, e);
    }
    #pragma unroll
    for (int off = 16; off; off >>= 1)
      lmax = fmaxf(lmax, __shfl_xor(lmax, off, 32));
    float nm = fmaxf(m, lmax);
    float scale = __expf(m - nm);  // first chunk: exp(-inf)=0
    denom *= scale;
    acc *= scale;
    float lsum = 0.f;
    for (int j = lane; j < n; j += 32) {
      float e = __expf(ex[head][j] - nm);
      ex[head][j] = e;
      lsum += e;
    }
    #pragma unroll
    for (int off = 16; off; off >>= 1)
      lsum += __shfl_xor(lsum, off, 32);
    denom += lsum;
    m = nm;
    __syncthreads();  // ex visible to whole block
    for (int j = 0; j < n; j++) {
      float w = ex[head][j];
      float vv = bf2f(*(const unsigned short*)(V + (size_t)cols[j] * HD +
                                               head * 32 + lane));
      acc += w * vv;
    }
  }
  float res = (end > start) ? acc / denom : 0.f;
  out[(size_t)node * HD + tid] = res;
}

extern "C" void kernel_launch(void* const* d_in, const int* in_sizes, int n_in,
                              void* d_out, int out_size, void* d_ws,
                              size_t ws_size, hipStream_t stream) {
  const float* h = (const float*)d_in[0];
  const int* edge = (const int*)d_in[1];
  const float* WQ = (const float*)d_in[2];
  const float* WK = (const float*)d_in[3];
  const float* WV = (const float*)d_in[4];
  float* out = (float*)d_out;

  int n_node = in_sizes[0] / D_IN;
  int n_edge = in_sizes[1] / 2;
  const int* row = edge;
  const int* col = edge + n_edge;

  char* ws = (char*)d_ws;
  size_t off = 0;
  auto alloc = [&](size_t bytes) {
    void* p = ws + off;
    off += (bytes + 255) & ~(size_t)255;
    return p;
  };
  __hip_bfloat16* Q = (__hip_bfloat16*)alloc((size_t)n_node * HD * 2);
  __hip_bfloat16* K = (__hip_bfloat16*)alloc((size_t)n_node * HD * 2);
  __hip_bfloat16* V = (__hip_bfloat16*)alloc((size_t)n_node * HD * 2);
  int* col_sorted = (int*)alloc((size_t)n_edge * 4);
  int* cnt = (int*)alloc((size_t)n_node * 4);
  int* offsets = (int*)alloc((size_t)(n_node + 1) * 4);
  int* cursor = (int*)alloc((size_t)n_node * 4);
  int* bsum = (int*)alloc(256 * 4);

  hipMemsetAsync(cnt, 0, (size_t)n_node * 4, stream);

  int nb_nodes8 = (n_node + 7) / 8;
  qkv_kernel<<<nb_nodes8, 256, 0, stream>>>(h, WQ, WK, WV, Q, K, V, n_node);

  int nb_e = (n_edge + 255) / 256;
  hist_kernel<<<nb_e, 256, 0, stream>>>(row, n_edge, cnt);

  int nb = (n_node + 255) / 256;
  scan1_kernel<<<nb, 256, 0, stream>>>(cnt, n_node, offsets, bsum);
  scan2_kernel<<<1, 256, 0, stream>>>(bsum, nb);
  scan3_kernel<<<nb, 256, 0, stream>>>(offsets, bsum, n_node, n_edge, cursor);

  scatter_kernel<<<nb_e, 256, 0, stream>>>(row, col, n_edge, cursor, col_sorted);

  attn_kernel<<<n_node, 256, 0, stream>>>(Q, K, V, offsets, col_sorted, out,
                                          n_node);
}